// Round 10
// baseline (297.454 us; speedup 1.0000x reference)
//
#include <hip/hip_runtime.h>

#define BATCH 4
#define CDIM 256
#define NDIM 4096
#define JT 32                    // keys per j-tile

typedef unsigned short u16;
typedef unsigned int u32;
typedef _Float16 f16;
typedef __attribute__((ext_vector_type(8))) _Float16 half8;
typedef __attribute__((ext_vector_type(4))) float floatx4;

__device__ __forceinline__ void load_lds_128(const void* g, void* l) {
  __builtin_amdgcn_global_load_lds(
      (const __attribute__((address_space(1))) u32*)g,
      (__attribute__((address_space(3))) u32*)l, 16, 0, 0);
}

// ---------------------------------------------------------------------------
// W (f32 [C][C]) -> fp16 [C][C], rows stay contraction-contiguous.
// ---------------------------------------------------------------------------
__global__ __launch_bounds__(256) void prep_w_k(
    const float* __restrict__ wq, const float* __restrict__ wk,
    const float* __restrict__ wv, f16* __restrict__ whq,
    f16* __restrict__ whk, f16* __restrict__ whv) {
  const int gid = blockIdx.x * 256 + threadIdx.x;  // 0..24575
  const int a = gid >> 13;
  const int r = gid & 8191;
  const float* src = (a == 0) ? wq : ((a == 1) ? wk : wv);
  f16* dst = (a == 0) ? whq : ((a == 1) ? whk : whv);
  float4 v0 = *(const float4*)(src + r * 8);
  float4 v1 = *(const float4*)(src + r * 8 + 4);
  half8 h;
  h[0] = (f16)v0.x; h[1] = (f16)v0.y; h[2] = (f16)v0.z; h[3] = (f16)v0.w;
  h[4] = (f16)v1.x; h[5] = (f16)v1.y; h[6] = (f16)v1.z; h[7] = (f16)v1.w;
  *(half8*)(dst + r * 8) = h;
}

// ---------------------------------------------------------------------------
// Fused transpose + projection, K/V merged, transposed LDS tile, 8 waves.
// grid (NDIM/128, BATCH, 2), block 512.
//   z=0: stage x1 tile -> Q projection
//   z=1: stage x2 tile ONCE -> K projection, then V projection (same xt)
// xtt[n][c]: 128 rows x 256 ch f16, stride 264 u16 (528 B, 16-B aligned).
// ---------------------------------------------------------------------------
__global__ __launch_bounds__(512, 2) void proj_fused_k(
    const float* __restrict__ x1, const float* __restrict__ x2,
    const f16* __restrict__ whq, const float* __restrict__ bq,
    const f16* __restrict__ whk, const float* __restrict__ bk,
    const f16* __restrict__ whv, const float* __restrict__ bv,
    f16* __restrict__ qt, f16* __restrict__ kt, f16* __restrict__ vsp) {
  __shared__ __align__(16) u16 xtt[128 * 264];  // 67584 B
  const int j0 = blockIdx.x * 128;
  const int b = blockIdx.y;
  const int z = blockIdx.z;
  const float* xs = ((z == 0) ? x1 : x2) + (size_t)b * CDIM * NDIM;
  const int t = threadIdx.x;
  const int wave = t >> 6, lane = t & 63, l16 = lane & 15, grp = lane >> 4;

  // ---- stage: task = wave + 8*it: c4 = task>>1, n = (task&1)*64 + lane ----
#pragma unroll
  for (int it = 0; it < 16; ++it) {
    const int task = wave + it * 8;        // 0..127
    const int c4 = task >> 1;              // channel group of 4
    const int n = (task & 1) * 64 + lane;  // column within tile
    const float* gp = xs + (size_t)(c4 * 4) * NDIM + j0 + n;
    float v0 = gp[0];
    float v1 = gp[NDIM];
    float v2 = gp[2 * NDIM];
    float v3 = gp[3 * NDIM];
    union { f16 h[4]; uint2 u; } pk;
    pk.h[0] = (f16)v0; pk.h[1] = (f16)v1; pk.h[2] = (f16)v2; pk.h[3] = (f16)v3;
    *(uint2*)&xtt[n * 264 + c4 * 4] = pk.u;
  }
  __syncthreads();
  const f16* xth = (const f16*)xtt;

  // ---- Q/K projection: wave = (j-range 32, c-half 128) ----
  {
    const f16* w = (z == 0) ? whq : whk;
    const float* bias = (z == 0) ? bq : bk;
    f16* outp = ((z == 0) ? qt : kt) + (size_t)b * NDIM * CDIM;
    const int jb0 = (wave & 3) * 32;       // j-range within tile
    const int cw = (wave >> 2) * 128;      // c-half
    floatx4 acc[2][8];
#pragma unroll
    for (int mb = 0; mb < 2; ++mb)
#pragma unroll
      for (int nb = 0; nb < 8; ++nb) acc[mb][nb] = (floatx4){0.f, 0.f, 0.f, 0.f};
#pragma unroll
    for (int ks = 0; ks < 8; ++ks) {
      half8 a[2];
#pragma unroll
      for (int mb = 0; mb < 2; ++mb) {
        const int n = jb0 + mb * 16 + l16;
        a[mb] = *(const half8*)&xth[n * 264 + ks * 32 + grp * 8];
      }
      __builtin_amdgcn_s_setprio(1);
#pragma unroll
      for (int nb = 0; nb < 8; ++nb) {
        half8 bb = *(const half8*)(w + (size_t)(cw + nb * 16 + l16) * CDIM + ks * 32 + grp * 8);
        acc[0][nb] = __builtin_amdgcn_mfma_f32_16x16x32_f16(a[0], bb, acc[0][nb], 0, 0, 0);
        acc[1][nb] = __builtin_amdgcn_mfma_f32_16x16x32_f16(a[1], bb, acc[1][nb], 0, 0, 0);
      }
      __builtin_amdgcn_s_setprio(0);
    }
#pragma unroll
    for (int nb = 0; nb < 8; ++nb) {
      const int c = cw + nb * 16 + l16;
      const float bvv = bias[c];
#pragma unroll
      for (int mb = 0; mb < 2; ++mb) {
        const int jbase = j0 + jb0 + mb * 16 + grp * 4;
#pragma unroll
        for (int r = 0; r < 4; ++r)
          outp[(size_t)(jbase + r) * CDIM + c] = (f16)(acc[mb][nb][r] + bvv);
      }
    }
  }

  // ---- V projection (z=1 only): wave = (c-half 128, j-quarter 32) ----
  if (z == 1) {
    f16* outp = vsp + (size_t)b * CDIM * NDIM;
    const int cw = (wave & 1) * 128;
    const int jw = (wave >> 1) * 32;
    floatx4 acc[8][2];
#pragma unroll
    for (int mb = 0; mb < 8; ++mb)
#pragma unroll
      for (int nb = 0; nb < 2; ++nb) acc[mb][nb] = (floatx4){0.f, 0.f, 0.f, 0.f};
#pragma unroll
    for (int ks = 0; ks < 8; ++ks) {
      half8 a[8];
#pragma unroll
      for (int mb = 0; mb < 8; ++mb)
        a[mb] = *(const half8*)(whv + (size_t)(cw + mb * 16 + l16) * CDIM + ks * 32 + grp * 8);
#pragma unroll
      for (int nb = 0; nb < 2; ++nb) {
        const int n = jw + nb * 16 + l16;
        half8 bv8 = *(const half8*)&xth[n * 264 + ks * 32 + grp * 8];
        __builtin_amdgcn_s_setprio(1);
#pragma unroll
        for (int mb = 0; mb < 8; ++mb)
          acc[mb][nb] = __builtin_amdgcn_mfma_f32_16x16x32_f16(a[mb], bv8, acc[mb][nb], 0, 0, 0);
        __builtin_amdgcn_s_setprio(0);
      }
    }
#pragma unroll
    for (int mb = 0; mb < 8; ++mb)
#pragma unroll
      for (int r = 0; r < 4; ++r) {
        const int c = cw + mb * 16 + grp * 4 + r;
        const float bvv = bv[c];
#pragma unroll
        for (int nb = 0; nb < 2; ++nb) {
          const int j = j0 + jw + nb * 16 + l16;
          outp[(size_t)c * NDIM + j] = (f16)(acc[mb][nb][r] + bvv);
        }
      }
  }
}

// ---------------------------------------------------------------------------
// Flash attention partial — single-buffered K/V for 3 blocks/CU occupancy:
//  - per-wave data path identical to the verified r7-r9 kernel (8 waves x
//    16 q; raw-S f16 LDS roundtrip; A-layout stats; skip-rescale; O^T PV;
//    setprio around MFMA clusters)
//  - single 32 KB K/V buffer + 10 KB P = 43 KB LDS -> 3 blocks/CU,
//    6 waves/SIMD (was 2 blocks / 4 waves). Cross-block phase overlap
//    replaces the intra-block double-buffer prefetch.
//  - SPL splits of the key dim; grid 32 q-tiles x (4 b x SPL).
// ---------------------------------------------------------------------------
template <int SPL>
__global__ __launch_bounds__(512, 4) void flash_k(
    const f16* __restrict__ qt, const f16* __restrict__ kt,
    const f16* __restrict__ vs, f16* __restrict__ pO,
    float* __restrict__ pm, float* __restrict__ pl) {
  constexpr int KSP = NDIM / SPL;
  constexpr int NT = KSP / JT;
  __shared__ __align__(16) u16 smem[16384 + 5120];  // 32 KB K/V + 10240 B P
  const int bx = blockIdx.x;
  const int cc = bx & (BATCH * SPL - 1);     // XCD-pinned (b,s)
  const int b = cc / SPL, s = cc % SPL;
  const int i0 = (bx / (BATCH * SPL)) * 128;
  const int jwin = s * KSP;
  const f16* Q = qt + (size_t)b * NDIM * CDIM;
  const f16* K = kt + (size_t)b * NDIM * CDIM;
  const f16* V = vs + (size_t)b * CDIM * NDIM;
  const int tid = threadIdx.x;
  const int wave = tid >> 6, lane = tid & 63, l16 = lane & 15, grp = lane >> 4;
  f16* Pw = (f16*)(smem + 16384) + wave * (16 * 40);  // 16 rows x 40 f16

  // persistent Q frags: 16 queries per wave
  half8 qf[8];
#pragma unroll
  for (int ks = 0; ks < 8; ++ks)
    qf[ks] = *(const half8*)(Q + (size_t)(i0 + wave * 16 + l16) * CDIM + ks * 32 + grp * 8);

  floatx4 O[16];  // O^T: row=channel-local grp*4+r, col=query l16
#pragma unroll
  for (int cb = 0; cb < 16; ++cb) O[cb] = (floatx4){0.f, 0.f, 0.f, 0.f};
  float m_ = -1e30f;
  float lsum = 0.f;

  const int kr2 = lane >> 5, kp = lane & 31;   // K staging: 2 rows/instr
  const int vrow = lane >> 2, vp = lane & 3;   // V staging: 16 rows/instr

#define STAGE(J0)                                                              \
  {                                                                            \
    u16* sK = smem;                                                            \
    u16* sV = smem + 8192;                                                     \
    _Pragma("unroll") for (int it = 0; it < 2; ++it) {                         \
      const int row = wave * 4 + it * 2 + kr2;                                 \
      const int g = kp ^ (row & 7);                                            \
      load_lds_128(K + (size_t)((J0) + row) * CDIM + g * 8,                    \
                   &sK[(wave * 4 + it * 2) * 256]);                            \
    }                                                                          \
    _Pragma("unroll") for (int it = 0; it < 2; ++it) {                         \
      const int c = wave * 32 + it * 16 + vrow;                                \
      const int g = vp ^ ((c >> 2) & 3);                                       \
      load_lds_128(V + (size_t)c * NDIM + (J0) + g * 8,                        \
                   &sV[(wave * 32 + it * 16) * 32]);                           \
    }                                                                          \
  }

  for (int tt = 0; tt < NT; ++tt) {
    STAGE(jwin + tt * JT)
    __syncthreads();  // drains staging; buffer valid
    u16* bK = smem;
    u16* bV = smem + 8192;

    // ---- S = Q K^T (C-layout: row=query grp*4+r, col=key l16) ----
    floatx4 S[2];
#pragma unroll
    for (int jb = 0; jb < 2; ++jb) S[jb] = (floatx4){0.f, 0.f, 0.f, 0.f};
    __builtin_amdgcn_s_setprio(1);
#pragma unroll
    for (int ks = 0; ks < 8; ++ks) {
      const int chunk = ks * 4 + grp;
#pragma unroll
      for (int jb = 0; jb < 2; ++jb) {
        const int row = jb * 16 + l16;
        half8 kf = *(const half8*)&bK[row * 256 + ((chunk ^ (row & 7)) << 3)];
        S[jb] = __builtin_amdgcn_mfma_f32_16x16x32_f16(qf[ks], kf, S[jb], 0, 0, 0);
      }
    }
    __builtin_amdgcn_s_setprio(0);

    // ---- raw-S (f16) roundtrip; stats + exp in A-layout; pa frag ----
#pragma unroll
    for (int jb = 0; jb < 2; ++jb)
#pragma unroll
      for (int r = 0; r < 4; ++r)
        Pw[(grp * 4 + r) * 40 + jb * 16 + l16] = (f16)S[jb][r];
    // lane reads 8 raw scores of query row l16 (cols grp*8..grp*8+7)
    half8 rawh = *(const half8*)&Pw[l16 * 40 + grp * 8];
    float u[8];
#pragma unroll
    for (int j = 0; j < 8; ++j) u[j] = (float)rawh[j];
    float mx = fmaxf(fmaxf(fmaxf(u[0], u[1]), fmaxf(u[2], u[3])),
                     fmaxf(fmaxf(u[4], u[5]), fmaxf(u[6], u[7])));
    mx = fmaxf(mx, __shfl_xor(mx, 16, 64));
    mx = fmaxf(mx, __shfl_xor(mx, 32, 64));
    const float mnew = fmaxf(m_, mx);
    const float alpha = __expf(m_ - mnew);
    m_ = mnew;
    float pe[8];
#pragma unroll
    for (int j = 0; j < 8; ++j) pe[j] = __expf(u[j] - mnew);
    const float ps = ((pe[0] + pe[1]) + (pe[2] + pe[3])) +
                     ((pe[4] + pe[5]) + (pe[6] + pe[7]));
    lsum = lsum * alpha + ps;
    half8 pa;
#pragma unroll
    for (int j = 0; j < 8; ++j) pa[j] = (f16)pe[j];

    // ---- rescale O^T (skip when maxes static) ----
    if (__any(alpha < 1.f)) {
#pragma unroll
      for (int cb = 0; cb < 16; ++cb) O[cb] *= alpha;
    }

    // ---- O^T += V * P^T : A=V rows (lane l16 = channel) ----
    __builtin_amdgcn_s_setprio(1);
#pragma unroll
    for (int cb = 0; cb < 16; ++cb) {
      const int c = cb * 16 + l16;
      half8 vf = *(const half8*)&bV[c * 32 + ((grp ^ ((c >> 2) & 3)) << 3)];
      O[cb] = __builtin_amdgcn_mfma_f32_16x16x32_f16(vf, pa, O[cb], 0, 0, 0);
    }
    __builtin_amdgcn_s_setprio(0);
    __syncthreads();  // all reads done before next tile's STAGE overwrites
  }

  // ---- final l reduce across the 4 grp lane-groups ----
  lsum += __shfl_xor(lsum, 16, 64);
  lsum += __shfl_xor(lsum, 32, 64);
  if (grp == 0) {
    const int base = (b * SPL + s) * NDIM + i0;
    const int i = wave * 16 + l16;
    pm[base + i] = m_;
    pl[base + i] = lsum;
  }

  // ---- epilogue: direct stores from O^T C-layout ----
  const size_t pbase = (size_t)(b * SPL + s) * CDIM * NDIM;
  const int i = i0 + wave * 16 + l16;
#pragma unroll
  for (int cb = 0; cb < 16; ++cb) {
    const int c = cb * 16 + grp * 4;
#pragma unroll
    for (int r = 0; r < 4; ++r)
      pO[pbase + (size_t)(c + r) * NDIM + i] = (f16)O[cb][r];
  }
}

// ---------------------------------------------------------------------------
// Combine SPL split partials: out[b][c][i] = sum_s u_s(i) * O_s[c][i]
// ---------------------------------------------------------------------------
template <int SPL>
__global__ __launch_bounds__(256) void combine_k(
    const f16* __restrict__ pO, const float* __restrict__ pm,
    const float* __restrict__ pl, float* __restrict__ out) {
  __shared__ float su[SPL][64];
  const int b = blockIdx.x >> 6;
  const int i0 = (blockIdx.x & 63) * 64;
  const int t = threadIdx.x;
  if (t < 64) {
    const int i = i0 + t;
    float mv[SPL], w[SPL];
    float M = -3e38f;
#pragma unroll
    for (int s = 0; s < SPL; ++s) {
      mv[s] = pm[(b * SPL + s) * NDIM + i];
      M = fmaxf(M, mv[s]);
    }
    float L = 0.f;
#pragma unroll
    for (int s = 0; s < SPL; ++s) {
      w[s] = __expf(mv[s] - M);
      L += pl[(b * SPL + s) * NDIM + i] * w[s];
    }
    const float invL = 1.0f / L;
#pragma unroll
    for (int s = 0; s < SPL; ++s) su[s][t] = w[s] * invL;
  }
  __syncthreads();
#pragma unroll
  for (int it = 0; it < 8; ++it) {
    const int task = t + it * 256;
    const int c = task >> 3, p = (task & 7) * 8;
    float acc[8] = {0.f, 0.f, 0.f, 0.f, 0.f, 0.f, 0.f, 0.f};
#pragma unroll
    for (int s = 0; s < SPL; ++s) {
      const f16* src = pO + ((size_t)(b * SPL + s) * CDIM + c) * NDIM + i0 + p;
      half8 h = *(const half8*)src;
#pragma unroll
      for (int j = 0; j < 8; ++j) acc[j] += su[s][p + j] * (float)h[j];
    }
    float* dst = out + ((size_t)b * CDIM + c) * NDIM + i0 + p;
    float4 lo = {acc[0], acc[1], acc[2], acc[3]};
    float4 hi = {acc[4], acc[5], acc[6], acc[7]};
    *(float4*)dst = lo;
    *(float4*)(dst + 4) = hi;
  }
}

// ---------------------------------------------------------------------------
extern "C" void kernel_launch(void* const* d_in, const int* in_sizes, int n_in,
                              void* d_out, int out_size, void* d_ws, size_t ws_size,
                              hipStream_t stream) {
  const float* x1 = (const float*)d_in[0];
  const float* x2 = (const float*)d_in[1];
  const float* Wq = (const float*)d_in[2];
  const float* bq = (const float*)d_in[3];
  const float* Wk = (const float*)d_in[4];
  const float* bk = (const float*)d_in[5];
  const float* Wv = (const float*)d_in[6];
  const float* bv = (const float*)d_in[7];
  float* out = (float*)d_out;
  char* ws = (char*)d_ws;
  f16* qtp = (f16*)(ws + 0);
  f16* ktp = (f16*)(ws + 8388608);
  f16* vsp = (f16*)(ws + 16777216);

  // big layout (SPL=8, verified r5): pO 67 MB @25165824, pm/pl @92274688/
  // 92798976, wh @93323264, total 93716480 B.
  const bool big = ws_size >= 93716480ull;

  f16* pO;
  float* pm;
  float* pl;
  f16* whq;
  if (big) {
    pO = (f16*)(ws + 25165824);
    pm = (float*)(ws + 92274688);
    pl = (float*)(ws + 92798976);
    whq = (f16*)(ws + 93323264);
  } else {
    pO = (f16*)(ws + 25165824);   // 32 MB region
    pm = (float*)(ws + 58720256);
    pl = (float*)(ws + 58982400);
    whq = (f16*)(ws + 41943040);  // dead pO space until flash (temporal reuse)
  }
  f16* whk = whq + CDIM * CDIM;
  f16* whv = whk + CDIM * CDIM;

  prep_w_k<<<dim3(96), dim3(256), 0, stream>>>(Wq, Wk, Wv, whq, whk, whv);
  proj_fused_k<<<dim3(NDIM / 128, BATCH, 2), dim3(512), 0, stream>>>(
      x1, x2, whq, bq, whk, bk, whv, bv, qtp, ktp, vsp);
  if (big) {
    // 32 q-tiles x (4 b x 8 split) = 1024 blocks -> 3 resident/CU (43 KB LDS)
    flash_k<8><<<dim3(1024), dim3(512), 0, stream>>>(qtp, ktp, vsp, pO, pm, pl);
    combine_k<8><<<dim3(256), dim3(256), 0, stream>>>(pO, pm, pl, out);
  } else {
    flash_k<4><<<dim3(512), dim3(512), 0, stream>>>(qtp, ktp, vsp, pO, pm, pl);
    combine_k<4><<<dim3(256), dim3(256), 0, stream>>>(pO, pm, pl, out);
  }
}

// Round 11
// 254.056 us; speedup vs baseline: 1.1708x; 1.1708x over previous
//
#include <hip/hip_runtime.h>

#define BATCH 4
#define CDIM 256
#define NDIM 4096
#define SPLITS 4
#define KSPLIT (NDIM / SPLITS)   // 1024 keys per split
#define JT 32                    // keys per j-tile
#define NTILES (KSPLIT / JT)     // 32

typedef unsigned short u16;
typedef unsigned int u32;
typedef _Float16 f16;
typedef __attribute__((ext_vector_type(8))) _Float16 half8;
typedef __attribute__((ext_vector_type(4))) float floatx4;

__device__ __forceinline__ void load_lds_128(const void* g, void* l) {
  __builtin_amdgcn_global_load_lds(
      (const __attribute__((address_space(1))) u32*)g,
      (__attribute__((address_space(3))) u32*)l, 16, 0, 0);
}

// ---------------------------------------------------------------------------
// W (f32 [C][C]) -> fp16 [C][C], rows stay contraction-contiguous.
// ---------------------------------------------------------------------------
__global__ __launch_bounds__(256) void prep_w_k(
    const float* __restrict__ wq, const float* __restrict__ wk,
    const float* __restrict__ wv, f16* __restrict__ whq,
    f16* __restrict__ whk, f16* __restrict__ whv) {
  const int gid = blockIdx.x * 256 + threadIdx.x;  // 0..24575
  const int a = gid >> 13;
  const int r = gid & 8191;
  const float* src = (a == 0) ? wq : ((a == 1) ? wk : wv);
  f16* dst = (a == 0) ? whq : ((a == 1) ? whk : whv);
  float4 v0 = *(const float4*)(src + r * 8);
  float4 v1 = *(const float4*)(src + r * 8 + 4);
  half8 h;
  h[0] = (f16)v0.x; h[1] = (f16)v0.y; h[2] = (f16)v0.z; h[3] = (f16)v0.w;
  h[4] = (f16)v1.x; h[5] = (f16)v1.y; h[6] = (f16)v1.z; h[7] = (f16)v1.w;
  *(half8*)(dst + r * 8) = h;
}

// ---------------------------------------------------------------------------
// Fused transpose + projection, K/V merged, transposed LDS tile, 8 waves.
// grid (NDIM/128, BATCH, 2), block 512.
//   z=0: stage x1 tile -> Q projection
//   z=1: stage x2 tile ONCE -> K projection, then V projection (same xt)
// xtt[n][c]: 128 rows x 256 ch f16, stride 264 u16 (528 B, 16-B aligned).
// ---------------------------------------------------------------------------
__global__ __launch_bounds__(512, 2) void proj_fused_k(
    const float* __restrict__ x1, const float* __restrict__ x2,
    const f16* __restrict__ whq, const float* __restrict__ bq,
    const f16* __restrict__ whk, const float* __restrict__ bk,
    const f16* __restrict__ whv, const float* __restrict__ bv,
    f16* __restrict__ qt, f16* __restrict__ kt, f16* __restrict__ vsp) {
  __shared__ __align__(16) u16 xtt[128 * 264];  // 67584 B
  const int j0 = blockIdx.x * 128;
  const int b = blockIdx.y;
  const int z = blockIdx.z;
  const float* xs = ((z == 0) ? x1 : x2) + (size_t)b * CDIM * NDIM;
  const int t = threadIdx.x;
  const int wave = t >> 6, lane = t & 63, l16 = lane & 15, grp = lane >> 4;

  // ---- stage: task = wave + 8*it: c4 = task>>1, n = (task&1)*64 + lane ----
#pragma unroll
  for (int it = 0; it < 16; ++it) {
    const int task = wave + it * 8;        // 0..127
    const int c4 = task >> 1;              // channel group of 4
    const int n = (task & 1) * 64 + lane;  // column within tile
    const float* gp = xs + (size_t)(c4 * 4) * NDIM + j0 + n;
    float v0 = gp[0];
    float v1 = gp[NDIM];
    float v2 = gp[2 * NDIM];
    float v3 = gp[3 * NDIM];
    union { f16 h[4]; uint2 u; } pk;
    pk.h[0] = (f16)v0; pk.h[1] = (f16)v1; pk.h[2] = (f16)v2; pk.h[3] = (f16)v3;
    *(uint2*)&xtt[n * 264 + c4 * 4] = pk.u;
  }
  __syncthreads();
  const f16* xth = (const f16*)xtt;

  // ---- Q/K projection: wave = (j-range 32, c-half 128) ----
  {
    const f16* w = (z == 0) ? whq : whk;
    const float* bias = (z == 0) ? bq : bk;
    f16* outp = ((z == 0) ? qt : kt) + (size_t)b * NDIM * CDIM;
    const int jb0 = (wave & 3) * 32;       // j-range within tile
    const int cw = (wave >> 2) * 128;      // c-half
    floatx4 acc[2][8];
#pragma unroll
    for (int mb = 0; mb < 2; ++mb)
#pragma unroll
      for (int nb = 0; nb < 8; ++nb) acc[mb][nb] = (floatx4){0.f, 0.f, 0.f, 0.f};
#pragma unroll
    for (int ks = 0; ks < 8; ++ks) {
      half8 a[2];
#pragma unroll
      for (int mb = 0; mb < 2; ++mb) {
        const int n = jb0 + mb * 16 + l16;
        a[mb] = *(const half8*)&xth[n * 264 + ks * 32 + grp * 8];
      }
      __builtin_amdgcn_s_setprio(1);
#pragma unroll
      for (int nb = 0; nb < 8; ++nb) {
        half8 bb = *(const half8*)(w + (size_t)(cw + nb * 16 + l16) * CDIM + ks * 32 + grp * 8);
        acc[0][nb] = __builtin_amdgcn_mfma_f32_16x16x32_f16(a[0], bb, acc[0][nb], 0, 0, 0);
        acc[1][nb] = __builtin_amdgcn_mfma_f32_16x16x32_f16(a[1], bb, acc[1][nb], 0, 0, 0);
      }
      __builtin_amdgcn_s_setprio(0);
    }
#pragma unroll
    for (int nb = 0; nb < 8; ++nb) {
      const int c = cw + nb * 16 + l16;
      const float bvv = bias[c];
#pragma unroll
      for (int mb = 0; mb < 2; ++mb) {
        const int jbase = j0 + jb0 + mb * 16 + grp * 4;
#pragma unroll
        for (int r = 0; r < 4; ++r)
          outp[(size_t)(jbase + r) * CDIM + c] = (f16)(acc[mb][nb][r] + bvv);
      }
    }
  }

  // ---- V projection (z=1 only): wave = (c-half 128, j-quarter 32) ----
  if (z == 1) {
    f16* outp = vsp + (size_t)b * CDIM * NDIM;
    const int cw = (wave & 1) * 128;
    const int jw = (wave >> 1) * 32;
    floatx4 acc[8][2];
#pragma unroll
    for (int mb = 0; mb < 8; ++mb)
#pragma unroll
      for (int nb = 0; nb < 2; ++nb) acc[mb][nb] = (floatx4){0.f, 0.f, 0.f, 0.f};
#pragma unroll
    for (int ks = 0; ks < 8; ++ks) {
      half8 a[8];
#pragma unroll
      for (int mb = 0; mb < 8; ++mb)
        a[mb] = *(const half8*)(whv + (size_t)(cw + mb * 16 + l16) * CDIM + ks * 32 + grp * 8);
#pragma unroll
      for (int nb = 0; nb < 2; ++nb) {
        const int n = jw + nb * 16 + l16;
        half8 bv8 = *(const half8*)&xth[n * 264 + ks * 32 + grp * 8];
        __builtin_amdgcn_s_setprio(1);
#pragma unroll
        for (int mb = 0; mb < 8; ++mb)
          acc[mb][nb] = __builtin_amdgcn_mfma_f32_16x16x32_f16(a[mb], bv8, acc[mb][nb], 0, 0, 0);
        __builtin_amdgcn_s_setprio(0);
      }
    }
#pragma unroll
    for (int mb = 0; mb < 8; ++mb)
#pragma unroll
      for (int r = 0; r < 4; ++r) {
        const int c = cw + mb * 16 + grp * 4 + r;
        const float bvv = bv[c];
#pragma unroll
        for (int nb = 0; nb < 2; ++nb) {
          const int j = j0 + jw + nb * 16 + l16;
          outp[(size_t)c * NDIM + j] = (f16)(acc[mb][nb][r] + bvv);
        }
      }
  }
}

// ---------------------------------------------------------------------------
// Flash attention partial — r9 verified structure (best: 134.5 us) + P-scratch
// XOR swizzle. Only change vs r9: the P write/read column-octet is XORed with
// the row's group (phys_col8 = col8 ^ (row>>2)), eliminating the 4-way
// ds_write_b16 bank conflict (rows g and g+2 shared bank sets at stride 80 B).
// Grid 512 = 32 q-tiles x (4 b x 4 split); block 512; dbuf + P = 75.8 KB.
// ---------------------------------------------------------------------------
__global__ __launch_bounds__(512, 4) void flash_k(
    const f16* __restrict__ qt, const f16* __restrict__ kt,
    const f16* __restrict__ vs, f16* __restrict__ pO,
    float* __restrict__ pm, float* __restrict__ pl) {
  __shared__ __align__(16) u16 smem[32768 + 5120];  // 64 KB dbuf + 10240 B P
  const int bx = blockIdx.x;
  const int c16 = bx & 15;                   // XCD-pinned (b,s)
  const int b = c16 >> 2, s = c16 & 3;
  const int i0 = (bx >> 4) * 128;
  const int jwin = s * KSPLIT;
  const f16* Q = qt + (size_t)b * NDIM * CDIM;
  const f16* K = kt + (size_t)b * NDIM * CDIM;
  const f16* V = vs + (size_t)b * CDIM * NDIM;
  const int tid = threadIdx.x;
  const int wave = tid >> 6, lane = tid & 63, l16 = lane & 15, grp = lane >> 4;
  f16* Pw = (f16*)(smem + 32768) + wave * (16 * 40);  // 16 rows x 40 f16

  // persistent Q frags: 16 queries per wave
  half8 qf[8];
#pragma unroll
  for (int ks = 0; ks < 8; ++ks)
    qf[ks] = *(const half8*)(Q + (size_t)(i0 + wave * 16 + l16) * CDIM + ks * 32 + grp * 8);

  floatx4 O[16];  // O^T: row=channel-local grp*4+r, col=query l16
#pragma unroll
  for (int cb = 0; cb < 16; ++cb) O[cb] = (floatx4){0.f, 0.f, 0.f, 0.f};
  float m_ = -1e30f;
  float lsum = 0.f;

  const int kr2 = lane >> 5, kp = lane & 31;   // K staging: 2 rows/instr
  const int vrow = lane >> 2, vp = lane & 3;   // V staging: 16 rows/instr

#define STAGE(J0, BUF)                                                         \
  {                                                                            \
    u16* sK = smem + (BUF) * 16384;                                            \
    u16* sV = sK + 8192;                                                       \
    _Pragma("unroll") for (int it = 0; it < 2; ++it) {                         \
      const int row = wave * 4 + it * 2 + kr2;                                 \
      const int g = kp ^ (row & 7);                                            \
      load_lds_128(K + (size_t)((J0) + row) * CDIM + g * 8,                    \
                   &sK[(wave * 4 + it * 2) * 256]);                            \
    }                                                                          \
    _Pragma("unroll") for (int it = 0; it < 2; ++it) {                         \
      const int c = wave * 32 + it * 16 + vrow;                                \
      const int g = vp ^ ((c >> 2) & 3);                                       \
      load_lds_128(V + (size_t)c * NDIM + (J0) + g * 8,                        \
                   &sV[(wave * 32 + it * 16) * 32]);                           \
    }                                                                          \
  }

  STAGE(jwin, 0)

  for (int tt = 0; tt < NTILES; ++tt) {
    __syncthreads();  // drains prefetch(tt); frees buffer (tt+1)&1
    if (tt + 1 < NTILES) STAGE(jwin + (tt + 1) * JT, (tt + 1) & 1)
    u16* bK = smem + (tt & 1) * 16384;
    u16* bV = bK + 8192;

    // ---- S = Q K^T (C-layout: row=query grp*4+r, col=key l16) ----
    floatx4 S[2];
#pragma unroll
    for (int jb = 0; jb < 2; ++jb) S[jb] = (floatx4){0.f, 0.f, 0.f, 0.f};
    __builtin_amdgcn_s_setprio(1);
#pragma unroll
    for (int ks = 0; ks < 8; ++ks) {
      const int chunk = ks * 4 + grp;
#pragma unroll
      for (int jb = 0; jb < 2; ++jb) {
        const int row = jb * 16 + l16;
        half8 kf = *(const half8*)&bK[row * 256 + ((chunk ^ (row & 7)) << 3)];
        S[jb] = __builtin_amdgcn_mfma_f32_16x16x32_f16(qf[ks], kf, S[jb], 0, 0, 0);
      }
    }
    __builtin_amdgcn_s_setprio(0);

    // ---- raw-S (f16) roundtrip, P-scratch XOR-swizzled ----
    // write: row=grp*4+r, col=jb*16+l16 -> phys octet = (col>>3) ^ grp
#pragma unroll
    for (int jb = 0; jb < 2; ++jb)
#pragma unroll
      for (int r = 0; r < 4; ++r) {
        const int col = jb * 16 + l16;
        Pw[(grp * 4 + r) * 40 + (((col >> 3) ^ grp) << 3) + (col & 7)] =
            (f16)S[jb][r];
      }
    // read: row=l16, logical octet grp -> phys octet grp ^ (l16>>2)
    half8 rawh = *(const half8*)&Pw[l16 * 40 + ((grp ^ (l16 >> 2)) << 3)];
    float u[8];
#pragma unroll
    for (int j = 0; j < 8; ++j) u[j] = (float)rawh[j];
    float mx = fmaxf(fmaxf(fmaxf(u[0], u[1]), fmaxf(u[2], u[3])),
                     fmaxf(fmaxf(u[4], u[5]), fmaxf(u[6], u[7])));
    mx = fmaxf(mx, __shfl_xor(mx, 16, 64));
    mx = fmaxf(mx, __shfl_xor(mx, 32, 64));
    const float mnew = fmaxf(m_, mx);
    const float alpha = __expf(m_ - mnew);
    m_ = mnew;
    float pe[8];
#pragma unroll
    for (int j = 0; j < 8; ++j) pe[j] = __expf(u[j] - mnew);
    const float ps = ((pe[0] + pe[1]) + (pe[2] + pe[3])) +
                     ((pe[4] + pe[5]) + (pe[6] + pe[7]));
    lsum = lsum * alpha + ps;
    half8 pa;
#pragma unroll
    for (int j = 0; j < 8; ++j) pa[j] = (f16)pe[j];

    // ---- rescale O^T (skip when maxes static) ----
    if (__any(alpha < 1.f)) {
#pragma unroll
      for (int cb = 0; cb < 16; ++cb) O[cb] *= alpha;
    }

    // ---- O^T += V * P^T : A=V rows (lane l16 = channel) ----
    __builtin_amdgcn_s_setprio(1);
#pragma unroll
    for (int cb = 0; cb < 16; ++cb) {
      const int c = cb * 16 + l16;
      half8 vf = *(const half8*)&bV[c * 32 + ((grp ^ ((c >> 2) & 3)) << 3)];
      O[cb] = __builtin_amdgcn_mfma_f32_16x16x32_f16(vf, pa, O[cb], 0, 0, 0);
    }
    __builtin_amdgcn_s_setprio(0);
  }

  // ---- final l reduce across the 4 grp lane-groups ----
  lsum += __shfl_xor(lsum, 16, 64);
  lsum += __shfl_xor(lsum, 32, 64);
  if (grp == 0) {
    const int base = (b * SPLITS + s) * NDIM + i0;
    const int i = wave * 16 + l16;
    pm[base + i] = m_;
    pl[base + i] = lsum;
  }

  // ---- epilogue: direct stores from O^T C-layout ----
  const size_t pbase = (size_t)(b * SPLITS + s) * CDIM * NDIM;
  const int i = i0 + wave * 16 + l16;
#pragma unroll
  for (int cb = 0; cb < 16; ++cb) {
    const int c = cb * 16 + grp * 4;
#pragma unroll
    for (int r = 0; r < 4; ++r)
      pO[pbase + (size_t)(c + r) * NDIM + i] = (f16)O[cb][r];
  }
}

// ---------------------------------------------------------------------------
// Combine 4 split partials: out[b][c][i] = sum_s u_s(i) * O_s[c][i]
// ---------------------------------------------------------------------------
__global__ __launch_bounds__(256) void combine_k(
    const f16* __restrict__ pO, const float* __restrict__ pm,
    const float* __restrict__ pl, float* __restrict__ out) {
  __shared__ float su[SPLITS][64];
  const int b = blockIdx.x >> 6;
  const int i0 = (blockIdx.x & 63) * 64;
  const int t = threadIdx.x;
  if (t < 64) {
    const int i = i0 + t;
    float mv[SPLITS], w[SPLITS];
    float M = -3e38f;
#pragma unroll
    for (int s = 0; s < SPLITS; ++s) {
      mv[s] = pm[(b * SPLITS + s) * NDIM + i];
      M = fmaxf(M, mv[s]);
    }
    float L = 0.f;
#pragma unroll
    for (int s = 0; s < SPLITS; ++s) {
      w[s] = __expf(mv[s] - M);
      L += pl[(b * SPLITS + s) * NDIM + i] * w[s];
    }
    const float invL = 1.0f / L;
#pragma unroll
    for (int s = 0; s < SPLITS; ++s) su[s][t] = w[s] * invL;
  }
  __syncthreads();
#pragma unroll
  for (int it = 0; it < 8; ++it) {
    const int task = t + it * 256;
    const int c = task >> 3, p = (task & 7) * 8;
    float acc[8] = {0.f, 0.f, 0.f, 0.f, 0.f, 0.f, 0.f, 0.f};
#pragma unroll
    for (int s = 0; s < SPLITS; ++s) {
      const f16* src = pO + ((size_t)(b * SPLITS + s) * CDIM + c) * NDIM + i0 + p;
      half8 h = *(const half8*)src;
#pragma unroll
      for (int j = 0; j < 8; ++j) acc[j] += su[s][p + j] * (float)h[j];
    }
    float* dst = out + ((size_t)b * CDIM + c) * NDIM + i0 + p;
    float4 lo = {acc[0], acc[1], acc[2], acc[3]};
    float4 hi = {acc[4], acc[5], acc[6], acc[7]};
    *(float4*)dst = lo;
    *(float4*)(dst + 4) = hi;
  }
}

// ---------------------------------------------------------------------------
extern "C" void kernel_launch(void* const* d_in, const int* in_sizes, int n_in,
                              void* d_out, int out_size, void* d_ws, size_t ws_size,
                              hipStream_t stream) {
  const float* x1 = (const float*)d_in[0];
  const float* x2 = (const float*)d_in[1];
  const float* Wq = (const float*)d_in[2];
  const float* bq = (const float*)d_in[3];
  const float* Wk = (const float*)d_in[4];
  const float* bk = (const float*)d_in[5];
  const float* Wv = (const float*)d_in[6];
  const float* bv = (const float*)d_in[7];
  float* out = (float*)d_out;
  char* ws = (char*)d_ws;
  f16* qtp = (f16*)(ws + 0);
  f16* ktp = (f16*)(ws + 8388608);
  f16* vsp = (f16*)(ws + 16777216);
  f16* pO = (f16*)(ws + 25165824);   // 32 MB region
  float* pm = (float*)(ws + 58720256);
  float* pl = (float*)(ws + 58982400);
  f16* whq = (f16*)(ws + 41943040);  // dead pO space until flash (temporal reuse)
  f16* whk = whq + CDIM * CDIM;
  f16* whv = whk + CDIM * CDIM;

  prep_w_k<<<dim3(96), dim3(256), 0, stream>>>(Wq, Wk, Wv, whq, whk, whv);
  proj_fused_k<<<dim3(NDIM / 128, BATCH, 2), dim3(512), 0, stream>>>(
      x1, x2, whq, bq, whk, bk, whv, bv, qtp, ktp, vsp);
  flash_k<<<dim3(512), dim3(512), 0, stream>>>(qtp, ktp, vsp, pO, pm, pl);
  combine_k<<<dim3(256), dim3(256), 0, stream>>>(pO, pm, pl, out);
}

// Round 12
// 248.332 us; speedup vs baseline: 1.1978x; 1.0230x over previous
//
#include <hip/hip_runtime.h>

#define BATCH 4
#define CDIM 256
#define NDIM 4096
#define SPLITS 4
#define KSPLIT (NDIM / SPLITS)   // 1024 keys per split
#define JT 32                    // keys per j-tile
#define NTILES (KSPLIT / JT)     // 32

typedef unsigned short u16;
typedef unsigned int u32;
typedef _Float16 f16;
typedef __attribute__((ext_vector_type(8))) _Float16 half8;
typedef __attribute__((ext_vector_type(4))) float floatx4;

__device__ __forceinline__ void load_lds_128(const void* g, void* l) {
  __builtin_amdgcn_global_load_lds(
      (const __attribute__((address_space(1))) u32*)g,
      (__attribute__((address_space(3))) u32*)l, 16, 0, 0);
}

// ---------------------------------------------------------------------------
// W (f32 [C][C]) -> fp16 [C][C], rows stay contraction-contiguous.
// ---------------------------------------------------------------------------
__global__ __launch_bounds__(256) void prep_w_k(
    const float* __restrict__ wq, const float* __restrict__ wk,
    const float* __restrict__ wv, f16* __restrict__ whq,
    f16* __restrict__ whk, f16* __restrict__ whv) {
  const int gid = blockIdx.x * 256 + threadIdx.x;  // 0..24575
  const int a = gid >> 13;
  const int r = gid & 8191;
  const float* src = (a == 0) ? wq : ((a == 1) ? wk : wv);
  f16* dst = (a == 0) ? whq : ((a == 1) ? whk : whv);
  float4 v0 = *(const float4*)(src + r * 8);
  float4 v1 = *(const float4*)(src + r * 8 + 4);
  half8 h;
  h[0] = (f16)v0.x; h[1] = (f16)v0.y; h[2] = (f16)v0.z; h[3] = (f16)v0.w;
  h[4] = (f16)v1.x; h[5] = (f16)v1.y; h[6] = (f16)v1.z; h[7] = (f16)v1.w;
  *(half8*)(dst + r * 8) = h;
}

// ---------------------------------------------------------------------------
// Fused transpose + projection, K/V merged, transposed LDS tile, 8 waves.
// grid (NDIM/128, BATCH, 2), block 512.
//   z=0: stage x1 tile -> Q projection
//   z=1: stage x2 tile ONCE -> K projection, then V projection (same xt)
// xtt[n][c]: 128 rows x 256 ch f16, stride 264 u16 (528 B, 16-B aligned).
// ---------------------------------------------------------------------------
__global__ __launch_bounds__(512, 2) void proj_fused_k(
    const float* __restrict__ x1, const float* __restrict__ x2,
    const f16* __restrict__ whq, const float* __restrict__ bq,
    const f16* __restrict__ whk, const float* __restrict__ bk,
    const f16* __restrict__ whv, const float* __restrict__ bv,
    f16* __restrict__ qt, f16* __restrict__ kt, f16* __restrict__ vsp) {
  __shared__ __align__(16) u16 xtt[128 * 264];  // 67584 B
  const int j0 = blockIdx.x * 128;
  const int b = blockIdx.y;
  const int z = blockIdx.z;
  const float* xs = ((z == 0) ? x1 : x2) + (size_t)b * CDIM * NDIM;
  const int t = threadIdx.x;
  const int wave = t >> 6, lane = t & 63, l16 = lane & 15, grp = lane >> 4;

  // ---- stage: task = wave + 8*it: c4 = task>>1, n = (task&1)*64 + lane ----
#pragma unroll
  for (int it = 0; it < 16; ++it) {
    const int task = wave + it * 8;        // 0..127
    const int c4 = task >> 1;              // channel group of 4
    const int n = (task & 1) * 64 + lane;  // column within tile
    const float* gp = xs + (size_t)(c4 * 4) * NDIM + j0 + n;
    float v0 = gp[0];
    float v1 = gp[NDIM];
    float v2 = gp[2 * NDIM];
    float v3 = gp[3 * NDIM];
    union { f16 h[4]; uint2 u; } pk;
    pk.h[0] = (f16)v0; pk.h[1] = (f16)v1; pk.h[2] = (f16)v2; pk.h[3] = (f16)v3;
    *(uint2*)&xtt[n * 264 + c4 * 4] = pk.u;
  }
  __syncthreads();
  const f16* xth = (const f16*)xtt;

  // ---- Q/K projection: wave = (j-range 32, c-half 128) ----
  {
    const f16* w = (z == 0) ? whq : whk;
    const float* bias = (z == 0) ? bq : bk;
    f16* outp = ((z == 0) ? qt : kt) + (size_t)b * NDIM * CDIM;
    const int jb0 = (wave & 3) * 32;       // j-range within tile
    const int cw = (wave >> 2) * 128;      // c-half
    floatx4 acc[2][8];
#pragma unroll
    for (int mb = 0; mb < 2; ++mb)
#pragma unroll
      for (int nb = 0; nb < 8; ++nb) acc[mb][nb] = (floatx4){0.f, 0.f, 0.f, 0.f};
#pragma unroll
    for (int ks = 0; ks < 8; ++ks) {
      half8 a[2];
#pragma unroll
      for (int mb = 0; mb < 2; ++mb) {
        const int n = jb0 + mb * 16 + l16;
        a[mb] = *(const half8*)&xth[n * 264 + ks * 32 + grp * 8];
      }
      __builtin_amdgcn_s_setprio(1);
#pragma unroll
      for (int nb = 0; nb < 8; ++nb) {
        half8 bb = *(const half8*)(w + (size_t)(cw + nb * 16 + l16) * CDIM + ks * 32 + grp * 8);
        acc[0][nb] = __builtin_amdgcn_mfma_f32_16x16x32_f16(a[0], bb, acc[0][nb], 0, 0, 0);
        acc[1][nb] = __builtin_amdgcn_mfma_f32_16x16x32_f16(a[1], bb, acc[1][nb], 0, 0, 0);
      }
      __builtin_amdgcn_s_setprio(0);
    }
#pragma unroll
    for (int nb = 0; nb < 8; ++nb) {
      const int c = cw + nb * 16 + l16;
      const float bvv = bias[c];
#pragma unroll
      for (int mb = 0; mb < 2; ++mb) {
        const int jbase = j0 + jb0 + mb * 16 + grp * 4;
#pragma unroll
        for (int r = 0; r < 4; ++r)
          outp[(size_t)(jbase + r) * CDIM + c] = (f16)(acc[mb][nb][r] + bvv);
      }
    }
  }

  // ---- V projection (z=1 only): wave = (c-half 128, j-quarter 32) ----
  if (z == 1) {
    f16* outp = vsp + (size_t)b * CDIM * NDIM;
    const int cw = (wave & 1) * 128;
    const int jw = (wave >> 1) * 32;
    floatx4 acc[8][2];
#pragma unroll
    for (int mb = 0; mb < 8; ++mb)
#pragma unroll
      for (int nb = 0; nb < 2; ++nb) acc[mb][nb] = (floatx4){0.f, 0.f, 0.f, 0.f};
#pragma unroll
    for (int ks = 0; ks < 8; ++ks) {
      half8 a[8];
#pragma unroll
      for (int mb = 0; mb < 8; ++mb)
        a[mb] = *(const half8*)(whv + (size_t)(cw + mb * 16 + l16) * CDIM + ks * 32 + grp * 8);
#pragma unroll
      for (int nb = 0; nb < 2; ++nb) {
        const int n = jw + nb * 16 + l16;
        half8 bv8 = *(const half8*)&xth[n * 264 + ks * 32 + grp * 8];
        __builtin_amdgcn_s_setprio(1);
#pragma unroll
        for (int mb = 0; mb < 8; ++mb)
          acc[mb][nb] = __builtin_amdgcn_mfma_f32_16x16x32_f16(a[mb], bv8, acc[mb][nb], 0, 0, 0);
        __builtin_amdgcn_s_setprio(0);
      }
    }
#pragma unroll
    for (int mb = 0; mb < 8; ++mb)
#pragma unroll
      for (int r = 0; r < 4; ++r) {
        const int c = cw + mb * 16 + grp * 4 + r;
        const float bvv = bv[c];
#pragma unroll
        for (int nb = 0; nb < 2; ++nb) {
          const int j = j0 + jw + nb * 16 + l16;
          outp[(size_t)c * NDIM + j] = (f16)(acc[mb][nb][r] + bvv);
        }
      }
  }
}

// ---------------------------------------------------------------------------
// Flash attention partial — r9 verified structure (best: 134.5 us) + T13
// defer-max (THR=8). Only change vs r9: the rescale fires only when some
// query's tile-max exceeds the running max by >8 (wave-uniform __all gate);
// otherwise m_ is kept and P <= e^8 (f16-safe, f32 accum). Saves the alpha
// exp + 64-wide O multiply + m update on most tiles.
// Grid 512 = 32 q-tiles x (4 b x 4 split); block 512; dbuf + P = 75.8 KB.
// ---------------------------------------------------------------------------
__global__ __launch_bounds__(512, 4) void flash_k(
    const f16* __restrict__ qt, const f16* __restrict__ kt,
    const f16* __restrict__ vs, f16* __restrict__ pO,
    float* __restrict__ pm, float* __restrict__ pl) {
  __shared__ __align__(16) u16 smem[32768 + 5120];  // 64 KB dbuf + 10240 B P
  const int bx = blockIdx.x;
  const int c16 = bx & 15;                   // XCD-pinned (b,s)
  const int b = c16 >> 2, s = c16 & 3;
  const int i0 = (bx >> 4) * 128;
  const int jwin = s * KSPLIT;
  const f16* Q = qt + (size_t)b * NDIM * CDIM;
  const f16* K = kt + (size_t)b * NDIM * CDIM;
  const f16* V = vs + (size_t)b * CDIM * NDIM;
  const int tid = threadIdx.x;
  const int wave = tid >> 6, lane = tid & 63, l16 = lane & 15, grp = lane >> 4;
  f16* Pw = (f16*)(smem + 32768) + wave * (16 * 40);  // 16 rows x 40 f16

  // persistent Q frags: 16 queries per wave
  half8 qf[8];
#pragma unroll
  for (int ks = 0; ks < 8; ++ks)
    qf[ks] = *(const half8*)(Q + (size_t)(i0 + wave * 16 + l16) * CDIM + ks * 32 + grp * 8);

  floatx4 O[16];  // O^T: row=channel-local grp*4+r, col=query l16
#pragma unroll
  for (int cb = 0; cb < 16; ++cb) O[cb] = (floatx4){0.f, 0.f, 0.f, 0.f};
  float m_ = -1e30f;
  float lsum = 0.f;

  const int kr2 = lane >> 5, kp = lane & 31;   // K staging: 2 rows/instr
  const int vrow = lane >> 2, vp = lane & 3;   // V staging: 16 rows/instr

#define STAGE(J0, BUF)                                                         \
  {                                                                            \
    u16* sK = smem + (BUF) * 16384;                                            \
    u16* sV = sK + 8192;                                                       \
    _Pragma("unroll") for (int it = 0; it < 2; ++it) {                         \
      const int row = wave * 4 + it * 2 + kr2;                                 \
      const int g = kp ^ (row & 7);                                            \
      load_lds_128(K + (size_t)((J0) + row) * CDIM + g * 8,                    \
                   &sK[(wave * 4 + it * 2) * 256]);                            \
    }                                                                          \
    _Pragma("unroll") for (int it = 0; it < 2; ++it) {                         \
      const int c = wave * 32 + it * 16 + vrow;                                \
      const int g = vp ^ ((c >> 2) & 3);                                       \
      load_lds_128(V + (size_t)c * NDIM + (J0) + g * 8,                        \
                   &sV[(wave * 32 + it * 16) * 32]);                           \
    }                                                                          \
  }

  STAGE(jwin, 0)

  for (int tt = 0; tt < NTILES; ++tt) {
    __syncthreads();  // drains prefetch(tt); frees buffer (tt+1)&1
    if (tt + 1 < NTILES) STAGE(jwin + (tt + 1) * JT, (tt + 1) & 1)
    u16* bK = smem + (tt & 1) * 16384;
    u16* bV = bK + 8192;

    // ---- S = Q K^T (C-layout: row=query grp*4+r, col=key l16) ----
    floatx4 S[2];
#pragma unroll
    for (int jb = 0; jb < 2; ++jb) S[jb] = (floatx4){0.f, 0.f, 0.f, 0.f};
    __builtin_amdgcn_s_setprio(1);
#pragma unroll
    for (int ks = 0; ks < 8; ++ks) {
      const int chunk = ks * 4 + grp;
#pragma unroll
      for (int jb = 0; jb < 2; ++jb) {
        const int row = jb * 16 + l16;
        half8 kf = *(const half8*)&bK[row * 256 + ((chunk ^ (row & 7)) << 3)];
        S[jb] = __builtin_amdgcn_mfma_f32_16x16x32_f16(qf[ks], kf, S[jb], 0, 0, 0);
      }
    }
    __builtin_amdgcn_s_setprio(0);

    // ---- raw-S (f16) roundtrip; stats + exp in A-layout; pa frag ----
#pragma unroll
    for (int jb = 0; jb < 2; ++jb)
#pragma unroll
      for (int r = 0; r < 4; ++r)
        Pw[(grp * 4 + r) * 40 + jb * 16 + l16] = (f16)S[jb][r];
    // lane reads 8 raw scores of query row l16 (cols grp*8..grp*8+7)
    half8 rawh = *(const half8*)&Pw[l16 * 40 + grp * 8];
    float u[8];
#pragma unroll
    for (int j = 0; j < 8; ++j) u[j] = (float)rawh[j];
    float mx = fmaxf(fmaxf(fmaxf(u[0], u[1]), fmaxf(u[2], u[3])),
                     fmaxf(fmaxf(u[4], u[5]), fmaxf(u[6], u[7])));
    mx = fmaxf(mx, __shfl_xor(mx, 16, 64));
    mx = fmaxf(mx, __shfl_xor(mx, 32, 64));
    // ---- defer-max (T13): rescale only when growth exceeds headroom ----
    if (!__all(mx - m_ <= 8.0f)) {
      const float mnew = fmaxf(m_, mx);
      const float alpha = __expf(m_ - mnew);
      m_ = mnew;
      lsum *= alpha;
#pragma unroll
      for (int cb = 0; cb < 16; ++cb) O[cb] *= alpha;
    }
    const float mm = m_;
    float pe[8];
#pragma unroll
    for (int j = 0; j < 8; ++j) pe[j] = __expf(u[j] - mm);
    const float ps = ((pe[0] + pe[1]) + (pe[2] + pe[3])) +
                     ((pe[4] + pe[5]) + (pe[6] + pe[7]));
    lsum += ps;
    half8 pa;
#pragma unroll
    for (int j = 0; j < 8; ++j) pa[j] = (f16)pe[j];

    // ---- O^T += V * P^T : A=V rows (lane l16 = channel) ----
    __builtin_amdgcn_s_setprio(1);
#pragma unroll
    for (int cb = 0; cb < 16; ++cb) {
      const int c = cb * 16 + l16;
      half8 vf = *(const half8*)&bV[c * 32 + ((grp ^ ((c >> 2) & 3)) << 3)];
      O[cb] = __builtin_amdgcn_mfma_f32_16x16x32_f16(vf, pa, O[cb], 0, 0, 0);
    }
    __builtin_amdgcn_s_setprio(0);
  }

  // ---- final l reduce across the 4 grp lane-groups ----
  lsum += __shfl_xor(lsum, 16, 64);
  lsum += __shfl_xor(lsum, 32, 64);
  if (grp == 0) {
    const int base = (b * SPLITS + s) * NDIM + i0;
    const int i = wave * 16 + l16;
    pm[base + i] = m_;
    pl[base + i] = lsum;
  }

  // ---- epilogue: direct stores from O^T C-layout ----
  const size_t pbase = (size_t)(b * SPLITS + s) * CDIM * NDIM;
  const int i = i0 + wave * 16 + l16;
#pragma unroll
  for (int cb = 0; cb < 16; ++cb) {
    const int c = cb * 16 + grp * 4;
#pragma unroll
    for (int r = 0; r < 4; ++r)
      pO[pbase + (size_t)(c + r) * NDIM + i] = (f16)O[cb][r];
  }
}

// ---------------------------------------------------------------------------
// Combine 4 split partials: out[b][c][i] = sum_s u_s(i) * O_s[c][i]
// ---------------------------------------------------------------------------
__global__ __launch_bounds__(256) void combine_k(
    const f16* __restrict__ pO, const float* __restrict__ pm,
    const float* __restrict__ pl, float* __restrict__ out) {
  __shared__ float su[SPLITS][64];
  const int b = blockIdx.x >> 6;
  const int i0 = (blockIdx.x & 63) * 64;
  const int t = threadIdx.x;
  if (t < 64) {
    const int i = i0 + t;
    float mv[SPLITS], w[SPLITS];
    float M = -3e38f;
#pragma unroll
    for (int s = 0; s < SPLITS; ++s) {
      mv[s] = pm[(b * SPLITS + s) * NDIM + i];
      M = fmaxf(M, mv[s]);
    }
    float L = 0.f;
#pragma unroll
    for (int s = 0; s < SPLITS; ++s) {
      w[s] = __expf(mv[s] - M);
      L += pl[(b * SPLITS + s) * NDIM + i] * w[s];
    }
    const float invL = 1.0f / L;
#pragma unroll
    for (int s = 0; s < SPLITS; ++s) su[s][t] = w[s] * invL;
  }
  __syncthreads();
#pragma unroll
  for (int it = 0; it < 8; ++it) {
    const int task = t + it * 256;
    const int c = task >> 3, p = (task & 7) * 8;
    float acc[8] = {0.f, 0.f, 0.f, 0.f, 0.f, 0.f, 0.f, 0.f};
#pragma unroll
    for (int s = 0; s < SPLITS; ++s) {
      const f16* src = pO + ((size_t)(b * SPLITS + s) * CDIM + c) * NDIM + i0 + p;
      half8 h = *(const half8*)src;
#pragma unroll
      for (int j = 0; j < 8; ++j) acc[j] += su[s][p + j] * (float)h[j];
    }
    float* dst = out + ((size_t)b * CDIM + c) * NDIM + i0 + p;
    float4 lo = {acc[0], acc[1], acc[2], acc[3]};
    float4 hi = {acc[4], acc[5], acc[6], acc[7]};
    *(float4*)dst = lo;
    *(float4*)(dst + 4) = hi;
  }
}

// ---------------------------------------------------------------------------
extern "C" void kernel_launch(void* const* d_in, const int* in_sizes, int n_in,
                              void* d_out, int out_size, void* d_ws, size_t ws_size,
                              hipStream_t stream) {
  const float* x1 = (const float*)d_in[0];
  const float* x2 = (const float*)d_in[1];
  const float* Wq = (const float*)d_in[2];
  const float* bq = (const float*)d_in[3];
  const float* Wk = (const float*)d_in[4];
  const float* bk = (const float*)d_in[5];
  const float* Wv = (const float*)d_in[6];
  const float* bv = (const float*)d_in[7];
  float* out = (float*)d_out;
  char* ws = (char*)d_ws;
  f16* qtp = (f16*)(ws + 0);
  f16* ktp = (f16*)(ws + 8388608);
  f16* vsp = (f16*)(ws + 16777216);
  f16* pO = (f16*)(ws + 25165824);   // 32 MB region
  float* pm = (float*)(ws + 58720256);
  float* pl = (float*)(ws + 58982400);
  f16* whq = (f16*)(ws + 41943040);  // dead pO space until flash (temporal reuse)
  f16* whk = whq + CDIM * CDIM;
  f16* whv = whk + CDIM * CDIM;

  prep_w_k<<<dim3(96), dim3(256), 0, stream>>>(Wq, Wk, Wv, whq, whk, whv);
  proj_fused_k<<<dim3(NDIM / 128, BATCH, 2), dim3(512), 0, stream>>>(
      x1, x2, whq, bq, whk, bk, whv, bv, qtp, ktp, vsp);
  flash_k<<<dim3(512), dim3(512), 0, stream>>>(qtp, ktp, vsp, pO, pm, pl);
  combine_k<<<dim3(256), dim3(256), 0, stream>>>(pO, pm, pl, out);
}